// Round 1
// baseline (302.371 us; speedup 1.0000x reference)
//
#include <hip/hip_runtime.h>

typedef __bf16 bf16;
typedef __attribute__((ext_vector_type(4))) __bf16 bf16x4;
typedef __attribute__((ext_vector_type(8))) __bf16 bf16x8;
typedef __attribute__((ext_vector_type(4))) float f32x4;

#define MFMA16(a, b, c) __builtin_amdgcn_mfma_f32_16x16x32_bf16((a), (b), (c), 0, 0, 0)

constexpr int BM  = 128;
constexpr int BK  = 64;
constexpr int LDT = 72;  // padded LDS row stride in bf16 (144 B = 9*16 B: 16B-aligned, bank-spread)

constexpr int N    = 8192;
constexpr int FEAT = 256;
constexpr int HID  = 64;

// Cacc[M][NCOL] += A[M][K] (f32, cvt->bf16 on stage) @ Bt[NCOL][K]^T (bf16)
// grid = (M/BM, ksplit); each block accumulates `ktiles` K-tiles of 64 then atomically flushes.
template <int NCOL>
__global__ __launch_bounds__(256) void gcn_mm(const float* __restrict__ A, int K,
                                              const bf16* __restrict__ Bt,
                                              float* __restrict__ Cacc, int ktiles) {
  __shared__ bf16 As[BM * LDT];
  __shared__ bf16 Bs[NCOL * LDT];
  const int tid = threadIdx.x;
  const int lane = tid & 63;
  const int wave = tid >> 6;
  const int i0 = blockIdx.x * BM;
  const int kbase = blockIdx.y * ktiles * BK;

  f32x4 acc[2][NCOL / 16] = {};

  for (int kt = 0; kt < ktiles; ++kt) {
    const int k0 = kbase + kt * BK;
    {  // stage A tile [128][64] f32 -> bf16
      const int rr = tid >> 4, c4 = tid & 15;
#pragma unroll
      for (int s = 0; s < 8; ++s) {
        const int row = rr + s * 16;
        const float4 v = *reinterpret_cast<const float4*>(&A[(size_t)(i0 + row) * K + k0 + c4 * 4]);
        bf16x4 o;
        o[0] = (bf16)v.x; o[1] = (bf16)v.y; o[2] = (bf16)v.z; o[3] = (bf16)v.w;
        *reinterpret_cast<bf16x4*>(&As[row * LDT + c4 * 4]) = o;
      }
    }
    {  // stage B tile [NCOL][64] bf16 (already [N][K] layout)
#pragma unroll
      for (int s = 0; s < NCOL / 32; ++s) {
        const int idx = tid + s * 256;
        const int n = idx >> 3, q = idx & 7;
        *reinterpret_cast<bf16x8*>(&Bs[n * LDT + q * 8]) =
            *reinterpret_cast<const bf16x8*>(&Bt[(size_t)n * K + k0 + q * 8]);
      }
    }
    __syncthreads();
    const int rA = wave * 32 + (lane & 15);
#pragma unroll
    for (int kk = 0; kk < 2; ++kk) {
      const int kb = kk * 32 + ((lane >> 4) << 3);
      const bf16x8 a0 = *reinterpret_cast<const bf16x8*>(&As[rA * LDT + kb]);
      const bf16x8 a1 = *reinterpret_cast<const bf16x8*>(&As[(rA + 16) * LDT + kb]);
#pragma unroll
      for (int n = 0; n < NCOL / 16; ++n) {
        const bf16x8 b = *reinterpret_cast<const bf16x8*>(&Bs[(n * 16 + (lane & 15)) * LDT + kb]);
        acc[0][n] = MFMA16(a0, b, acc[0][n]);
        acc[1][n] = MFMA16(a1, b, acc[1][n]);
      }
    }
    __syncthreads();
  }
  // C/D layout (m89-verified): col = lane&15, row = (lane>>4)*4 + reg
  const int r4 = (lane >> 4) << 2, col = lane & 15;
#pragma unroll
  for (int m = 0; m < 2; ++m)
#pragma unroll
    for (int n = 0; n < NCOL / 16; ++n)
#pragma unroll
      for (int r = 0; r < 4; ++r)
        atomicAdd(&Cacc[(size_t)(i0 + wave * 32 + m * 16 + r4 + r) * NCOL + n * 16 + col],
                  acc[m][n][r]);
}

// W1 [256][64] f32 -> W1T [64][256] bf16
__global__ void prep_w1t(const float* __restrict__ W1, bf16* __restrict__ W1T) {
  const int idx = blockIdx.x * 256 + threadIdx.x;  // 16384 total
  const int j = idx >> 8, k = idx & 255;
  W1T[idx] = (bf16)W1[k * HID + j];
}

// s1acc [8192][64] f32 -> S1T [64][8192] bf16 (tile-transpose via LDS)
__global__ __launch_bounds__(256) void transpose_bf16_64(const float* __restrict__ in,
                                                         bf16* __restrict__ out) {
  __shared__ float t[64][65];
  const int i0 = blockIdx.x * 64;
  const int tid = threadIdx.x;
#pragma unroll
  for (int s = 0; s < 4; ++s) {
    const int idx = tid + s * 256;  // 1024 float4 chunks
    const int row = idx >> 4, c4 = idx & 15;
    const float4 v = *reinterpret_cast<const float4*>(&in[(size_t)(i0 + row) * HID + c4 * 4]);
    t[row][c4 * 4 + 0] = v.x; t[row][c4 * 4 + 1] = v.y;
    t[row][c4 * 4 + 2] = v.z; t[row][c4 * 4 + 3] = v.w;
  }
  __syncthreads();
#pragma unroll
  for (int s = 0; s < 2; ++s) {
    const int idx = tid + s * 256;  // 512 chunks of 8 bf16
    const int j = idx >> 3, q = idx & 7;
    bf16x8 o;
#pragma unroll
    for (int e = 0; e < 8; ++e) o[e] = (bf16)t[q * 8 + e][j];
    *reinterpret_cast<bf16x8*>(&out[(size_t)j * N + i0 + q * 8]) = o;
  }
}

// s23T[j][i] = sum_c relu(h1acc[i][c]) * [W2|W3][c][j]   (j in [0,128))
__global__ __launch_bounds__(256) void relu_w23_t(const float* __restrict__ h1acc,
                                                  const float* __restrict__ W2,
                                                  const float* __restrict__ W3,
                                                  bf16* __restrict__ s23T) {
  __shared__ float Hs[32][65];
  __shared__ float Ws[64][128];
  const int i0 = blockIdx.x * 32;
  const int tid = threadIdx.x;
#pragma unroll
  for (int s = 0; s < 32; ++s) {  // stage W23: 8192 f32
    const int idx = tid + s * 256;
    const int c = idx >> 7, j = idx & 127;
    Ws[c][j] = (j < 64) ? W2[c * HID + j] : W3[c * HID + (j - 64)];
  }
#pragma unroll
  for (int s = 0; s < 8; ++s) {  // stage relu(h1) tile: 32x64 f32
    const int idx = tid + s * 256;
    const int r = idx >> 6, c = idx & 63;
    Hs[r][c] = fmaxf(h1acc[(size_t)(i0 + r) * HID + c], 0.0f);
  }
  __syncthreads();
  const int j = tid & 127, ih = tid >> 7;
  for (int ii = ih; ii < 32; ii += 2) {
    float a = 0.0f;
#pragma unroll
    for (int c = 0; c < 64; ++c) a += Hs[ii][c] * Ws[c][j];
    s23T[(size_t)j * N + i0 + ii] = (bf16)a;
  }
}

// mvacc [8192][128] -> mu [8192][64] f32, logvar [8192][64] f32
__global__ void epilogue_mu_lv(const float* __restrict__ mvacc, float* __restrict__ mu,
                               float* __restrict__ lv) {
  const int g = blockIdx.x * 256 + threadIdx.x;  // 8192*128
  const int i = g >> 7, j = g & 127;
  const float v = mvacc[g];
  if (j < 64)
    mu[i * HID + j] = v;
  else
    lv[i * HID + (j - 64)] = v;
}

// recon[i][j] = dot(mu[i,:], mu[j,:]) ; mu read as f32, cvt bf16, K=64
__global__ __launch_bounds__(256) void recon_mm(const float* __restrict__ mu,
                                                float* __restrict__ out) {
  __shared__ bf16 Am[BM * LDT];
  __shared__ bf16 Bm[BM * LDT];
  const int tid = threadIdx.x, lane = tid & 63, wave = tid >> 6;
  const int i0 = blockIdx.x * 128, j0 = blockIdx.y * 128;
  {
    const int rr = tid >> 4, c4 = tid & 15;
#pragma unroll
    for (int s = 0; s < 8; ++s) {
      const int row = rr + s * 16;
      const float4 v = *reinterpret_cast<const float4*>(&mu[(size_t)(i0 + row) * HID + c4 * 4]);
      bf16x4 o;
      o[0] = (bf16)v.x; o[1] = (bf16)v.y; o[2] = (bf16)v.z; o[3] = (bf16)v.w;
      *reinterpret_cast<bf16x4*>(&Am[row * LDT + c4 * 4]) = o;
      const float4 w = *reinterpret_cast<const float4*>(&mu[(size_t)(j0 + row) * HID + c4 * 4]);
      bf16x4 p;
      p[0] = (bf16)w.x; p[1] = (bf16)w.y; p[2] = (bf16)w.z; p[3] = (bf16)w.w;
      *reinterpret_cast<bf16x4*>(&Bm[row * LDT + c4 * 4]) = p;
    }
  }
  __syncthreads();
  f32x4 acc[2][8] = {};
  const int rA = wave * 32 + (lane & 15);
#pragma unroll
  for (int kk = 0; kk < 2; ++kk) {
    const int kb = kk * 32 + ((lane >> 4) << 3);
    const bf16x8 a0 = *reinterpret_cast<const bf16x8*>(&Am[rA * LDT + kb]);
    const bf16x8 a1 = *reinterpret_cast<const bf16x8*>(&Am[(rA + 16) * LDT + kb]);
#pragma unroll
    for (int n = 0; n < 8; ++n) {
      const bf16x8 b = *reinterpret_cast<const bf16x8*>(&Bm[(n * 16 + (lane & 15)) * LDT + kb]);
      acc[0][n] = MFMA16(a0, b, acc[0][n]);
      acc[1][n] = MFMA16(a1, b, acc[1][n]);
    }
  }
  const int r4 = (lane >> 4) << 2, c = lane & 15;
#pragma unroll
  for (int m = 0; m < 2; ++m)
#pragma unroll
    for (int n = 0; n < 8; ++n)
#pragma unroll
      for (int r = 0; r < 4; ++r)
        out[(size_t)(i0 + wave * 32 + m * 16 + r4 + r) * N + j0 + n * 16 + c] = acc[m][n][r];
}

extern "C" void kernel_launch(void* const* d_in, const int* in_sizes, int n_in, void* d_out,
                              int out_size, void* d_ws, size_t ws_size, hipStream_t stream) {
  const float* x   = (const float*)d_in[0];
  const float* adj = (const float*)d_in[1];
  const float* W1  = (const float*)d_in[2];
  const float* W2  = (const float*)d_in[3];
  const float* W3  = (const float*)d_in[4];

  float* out    = (float*)d_out;
  float* recon  = out;                          // [8192][8192]
  float* mu_out = out + (size_t)N * N;          // [8192][64]
  float* lv_out = mu_out + (size_t)N * HID;     // [8192][64]

  // Scratch lives inside the recon region of d_out (first ~12 MB): every
  // scratch buffer is dead before recon_mm overwrites the region.
  char* scr    = (char*)d_out;
  bf16*  S1T   = (bf16*)(scr + 0);                    // [64][8192]  1 MB
  float* s1acc = (float*)(scr + (1u << 20));          // [8192][64]  2 MB
  float* h1acc = (float*)(scr + (3u << 20));          // [8192][64]  2 MB
  bf16*  s23T  = (bf16*)(scr + (5u << 20));           // [128][8192] 2 MB
  float* mvacc = (float*)(scr + (7u << 20));          // [8192][128] 4 MB
  bf16*  W1T   = (bf16*)(scr + (11u << 20));          // [64][256]   32 KB

  hipMemsetAsync(s1acc, 0, (size_t)N * HID * 4, stream);
  hipMemsetAsync(h1acc, 0, (size_t)N * HID * 4, stream);
  hipMemsetAsync(mvacc, 0, (size_t)N * 2 * HID * 4, stream);

  prep_w1t<<<64, 256, 0, stream>>>(W1, W1T);
  // s1 = x @ W1
  gcn_mm<64><<<dim3(64, 1), 256, 0, stream>>>(x, FEAT, W1T, s1acc, FEAT / BK);
  transpose_bf16_64<<<128, 256, 0, stream>>>(s1acc, S1T);
  // h1acc = adj @ s1
  gcn_mm<64><<<dim3(64, 16), 256, 0, stream>>>(adj, N, S1T, h1acc, (N / 16) / BK);
  // s23T = (relu(h1acc) @ [W2|W3])^T
  relu_w23_t<<<256, 256, 0, stream>>>(h1acc, W2, W3, s23T);
  // mvacc = adj @ s23
  gcn_mm<128><<<dim3(64, 16), 256, 0, stream>>>(adj, N, s23T, mvacc, (N / 16) / BK);
  epilogue_mu_lv<<<4096, 256, 0, stream>>>(mvacc, mu_out, lv_out);
  // recon = mu @ mu^T
  recon_mm<<<dim3(64, 64), 256, 0, stream>>>(mu_out, recon);
}

// Round 2
// 290.666 us; speedup vs baseline: 1.0403x; 1.0403x over previous
//
#include <hip/hip_runtime.h>

typedef __bf16 bf16;
typedef __attribute__((ext_vector_type(4))) __bf16 bf16x4;
typedef __attribute__((ext_vector_type(8))) __bf16 bf16x8;
typedef __attribute__((ext_vector_type(4))) float f32x4;

#define MFMA16(a, b, c) __builtin_amdgcn_mfma_f32_16x16x32_bf16((a), (b), (c), 0, 0, 0)

constexpr int BM  = 128;
constexpr int BK  = 64;
constexpr int LDT = 72;  // padded LDS row stride in bf16 (144 B = 9*16 B: 16B-aligned, bank-spread)

constexpr int N    = 8192;
constexpr int FEAT = 256;
constexpr int HID  = 64;

// Cacc[M][NCOL] += A[M][K] @ Bt[NCOL][K]^T.
// A is f32 (cvt->bf16 on stage) when AF32, else bf16 (Abf).
// When WRITEB, the converted bf16 A-tile is also written to Aout (each tile is
// staged exactly once across the split-K grid, so this is a deterministic
// single full conversion of A).
// grid = (M/BM, ksplit); each block accumulates `ktiles` K-tiles then atomically flushes.
template <int NCOL, bool AF32, bool WRITEB>
__global__ __launch_bounds__(256) void gcn_mm(const float* __restrict__ A,
                                              const bf16* __restrict__ Abf, int K,
                                              const bf16* __restrict__ Bt,
                                              float* __restrict__ Cacc, int ktiles,
                                              bf16* __restrict__ Aout) {
  __shared__ bf16 As[BM * LDT];
  __shared__ bf16 Bs[NCOL * LDT];
  const int tid = threadIdx.x;
  const int lane = tid & 63;
  const int wave = tid >> 6;
  const int i0 = blockIdx.x * BM;
  const int kbase = blockIdx.y * ktiles * BK;

  f32x4 acc[2][NCOL / 16] = {};

  for (int kt = 0; kt < ktiles; ++kt) {
    const int k0 = kbase + kt * BK;
    if constexpr (AF32) {  // stage A tile [128][64] f32 -> bf16
      const int rr = tid >> 4, c4 = tid & 15;
#pragma unroll
      for (int s = 0; s < 8; ++s) {
        const int row = rr + s * 16;
        const float4 v = *reinterpret_cast<const float4*>(&A[(size_t)(i0 + row) * K + k0 + c4 * 4]);
        bf16x4 o;
        o[0] = (bf16)v.x; o[1] = (bf16)v.y; o[2] = (bf16)v.z; o[3] = (bf16)v.w;
        *reinterpret_cast<bf16x4*>(&As[row * LDT + c4 * 4]) = o;
        if constexpr (WRITEB)
          *reinterpret_cast<bf16x4*>(&Aout[(size_t)(i0 + row) * K + k0 + c4 * 4]) = o;
      }
    } else {  // stage A tile [128][64] bf16 directly
#pragma unroll
      for (int s = 0; s < 4; ++s) {
        const int idx = tid + s * 256;
        const int row = idx >> 3, q = idx & 7;
        *reinterpret_cast<bf16x8*>(&As[row * LDT + q * 8]) =
            *reinterpret_cast<const bf16x8*>(&Abf[(size_t)(i0 + row) * K + k0 + q * 8]);
      }
    }
    {  // stage B tile [NCOL][64] bf16 (already [N][K] layout)
#pragma unroll
      for (int s = 0; s < NCOL / 32; ++s) {
        const int idx = tid + s * 256;
        const int n = idx >> 3, q = idx & 7;
        *reinterpret_cast<bf16x8*>(&Bs[n * LDT + q * 8]) =
            *reinterpret_cast<const bf16x8*>(&Bt[(size_t)n * K + k0 + q * 8]);
      }
    }
    __syncthreads();
    const int rA = wave * 32 + (lane & 15);
#pragma unroll
    for (int kk = 0; kk < 2; ++kk) {
      const int kb = kk * 32 + ((lane >> 4) << 3);
      const bf16x8 a0 = *reinterpret_cast<const bf16x8*>(&As[rA * LDT + kb]);
      const bf16x8 a1 = *reinterpret_cast<const bf16x8*>(&As[(rA + 16) * LDT + kb]);
#pragma unroll
      for (int n = 0; n < NCOL / 16; ++n) {
        const bf16x8 b = *reinterpret_cast<const bf16x8*>(&Bs[(n * 16 + (lane & 15)) * LDT + kb]);
        acc[0][n] = MFMA16(a0, b, acc[0][n]);
        acc[1][n] = MFMA16(a1, b, acc[1][n]);
      }
    }
    __syncthreads();
  }
  // C/D layout (m89-verified): col = lane&15, row = (lane>>4)*4 + reg
  const int r4 = (lane >> 4) << 2, col = lane & 15;
#pragma unroll
  for (int m = 0; m < 2; ++m)
#pragma unroll
    for (int n = 0; n < NCOL / 16; ++n)
#pragma unroll
      for (int r = 0; r < 4; ++r)
        atomicAdd(&Cacc[(size_t)(i0 + wave * 32 + m * 16 + r4 + r) * NCOL + n * 16 + col],
                  acc[m][n][r]);
}

// fast zero-fill: one float4 per thread
__global__ void zero_fill(float4* __restrict__ p) {
  p[(size_t)blockIdx.x * 256 + threadIdx.x] = float4{0.f, 0.f, 0.f, 0.f};
}

// W1 [256][64] f32 -> W1T [64][256] bf16
__global__ void prep_w1t(const float* __restrict__ W1, bf16* __restrict__ W1T) {
  const int idx = blockIdx.x * 256 + threadIdx.x;  // 16384 total
  const int j = idx >> 8, k = idx & 255;
  W1T[idx] = (bf16)W1[k * HID + j];
}

// s1acc [8192][64] f32 -> S1T [64][8192] bf16 (tile-transpose via LDS)
__global__ __launch_bounds__(256) void transpose_bf16_64(const float* __restrict__ in,
                                                         bf16* __restrict__ out) {
  __shared__ float t[64][65];
  const int i0 = blockIdx.x * 64;
  const int tid = threadIdx.x;
#pragma unroll
  for (int s = 0; s < 4; ++s) {
    const int idx = tid + s * 256;  // 1024 float4 chunks
    const int row = idx >> 4, c4 = idx & 15;
    const float4 v = *reinterpret_cast<const float4*>(&in[(size_t)(i0 + row) * HID + c4 * 4]);
    t[row][c4 * 4 + 0] = v.x; t[row][c4 * 4 + 1] = v.y;
    t[row][c4 * 4 + 2] = v.z; t[row][c4 * 4 + 3] = v.w;
  }
  __syncthreads();
#pragma unroll
  for (int s = 0; s < 2; ++s) {
    const int idx = tid + s * 256;  // 512 chunks of 8 bf16
    const int j = idx >> 3, q = idx & 7;
    bf16x8 o;
#pragma unroll
    for (int e = 0; e < 8; ++e) o[e] = (bf16)t[q * 8 + e][j];
    *reinterpret_cast<bf16x8*>(&out[(size_t)j * N + i0 + q * 8]) = o;
  }
}

// s23T[j][i] = sum_c relu(h1acc[i][c]) * [W2|W3][c][j]   (j in [0,128))
__global__ __launch_bounds__(256) void relu_w23_t(const float* __restrict__ h1acc,
                                                  const float* __restrict__ W2,
                                                  const float* __restrict__ W3,
                                                  bf16* __restrict__ s23T) {
  __shared__ float Hs[32][65];
  __shared__ float Ws[64][128];
  const int i0 = blockIdx.x * 32;
  const int tid = threadIdx.x;
#pragma unroll
  for (int s = 0; s < 32; ++s) {  // stage W23: 8192 f32
    const int idx = tid + s * 256;
    const int c = idx >> 7, j = idx & 127;
    Ws[c][j] = (j < 64) ? W2[c * HID + j] : W3[c * HID + (j - 64)];
  }
#pragma unroll
  for (int s = 0; s < 8; ++s) {  // stage relu(h1) tile: 32x64 f32
    const int idx = tid + s * 256;
    const int r = idx >> 6, c = idx & 63;
    Hs[r][c] = fmaxf(h1acc[(size_t)(i0 + r) * HID + c], 0.0f);
  }
  __syncthreads();
  const int j = tid & 127, ih = tid >> 7;
  for (int ii = ih; ii < 32; ii += 2) {
    float a = 0.0f;
#pragma unroll
    for (int c = 0; c < 64; ++c) a += Hs[ii][c] * Ws[c][j];
    s23T[(size_t)j * N + i0 + ii] = (bf16)a;
  }
}

// mvacc [8192][128] -> mu [8192][64] f32, logvar [8192][64] f32
__global__ void epilogue_mu_lv(const float* __restrict__ mvacc, float* __restrict__ mu,
                               float* __restrict__ lv) {
  const int g = blockIdx.x * 256 + threadIdx.x;  // 8192*128
  const int i = g >> 7, j = g & 127;
  const float v = mvacc[g];
  if (j < 64)
    mu[i * HID + j] = v;
  else
    lv[i * HID + (j - 64)] = v;
}

// recon[i][j] = dot(mu[i,:], mu[j,:]) ; mu read as f32, cvt bf16, K=64
__global__ __launch_bounds__(256) void recon_mm(const float* __restrict__ mu,
                                                float* __restrict__ out) {
  __shared__ bf16 Am[BM * LDT];
  __shared__ bf16 Bm[BM * LDT];
  const int tid = threadIdx.x, lane = tid & 63, wave = tid >> 6;
  const int i0 = blockIdx.x * 128, j0 = blockIdx.y * 128;
  {
    const int rr = tid >> 4, c4 = tid & 15;
#pragma unroll
    for (int s = 0; s < 8; ++s) {
      const int row = rr + s * 16;
      const float4 v = *reinterpret_cast<const float4*>(&mu[(size_t)(i0 + row) * HID + c4 * 4]);
      bf16x4 o;
      o[0] = (bf16)v.x; o[1] = (bf16)v.y; o[2] = (bf16)v.z; o[3] = (bf16)v.w;
      *reinterpret_cast<bf16x4*>(&Am[row * LDT + c4 * 4]) = o;
      const float4 w = *reinterpret_cast<const float4*>(&mu[(size_t)(j0 + row) * HID + c4 * 4]);
      bf16x4 p;
      p[0] = (bf16)w.x; p[1] = (bf16)w.y; p[2] = (bf16)w.z; p[3] = (bf16)w.w;
      *reinterpret_cast<bf16x4*>(&Bm[row * LDT + c4 * 4]) = p;
    }
  }
  __syncthreads();
  f32x4 acc[2][8] = {};
  const int rA = wave * 32 + (lane & 15);
#pragma unroll
  for (int kk = 0; kk < 2; ++kk) {
    const int kb = kk * 32 + ((lane >> 4) << 3);
    const bf16x8 a0 = *reinterpret_cast<const bf16x8*>(&Am[rA * LDT + kb]);
    const bf16x8 a1 = *reinterpret_cast<const bf16x8*>(&Am[(rA + 16) * LDT + kb]);
#pragma unroll
    for (int n = 0; n < 8; ++n) {
      const bf16x8 b = *reinterpret_cast<const bf16x8*>(&Bm[(n * 16 + (lane & 15)) * LDT + kb]);
      acc[0][n] = MFMA16(a0, b, acc[0][n]);
      acc[1][n] = MFMA16(a1, b, acc[1][n]);
    }
  }
  const int r4 = (lane >> 4) << 2, c = lane & 15;
#pragma unroll
  for (int m = 0; m < 2; ++m)
#pragma unroll
    for (int n = 0; n < 8; ++n)
#pragma unroll
      for (int r = 0; r < 4; ++r)
        out[(size_t)(i0 + wave * 32 + m * 16 + r4 + r) * N + j0 + n * 16 + c] = acc[m][n][r];
}

extern "C" void kernel_launch(void* const* d_in, const int* in_sizes, int n_in, void* d_out,
                              int out_size, void* d_ws, size_t ws_size, hipStream_t stream) {
  const float* x   = (const float*)d_in[0];
  const float* adj = (const float*)d_in[1];
  const float* W1  = (const float*)d_in[2];
  const float* W2  = (const float*)d_in[3];
  const float* W3  = (const float*)d_in[4];

  float* out    = (float*)d_out;
  float* recon  = out;                          // [8192][8192]
  float* mu_out = out + (size_t)N * N;          // [8192][64]
  float* lv_out = mu_out + (size_t)N * HID;     // [8192][64]

  // Scratch lives inside the recon region of d_out (first ~150 MB of 256 MiB):
  // every scratch buffer is dead before recon_mm overwrites the region.
  char* scr    = (char*)d_out;
  bf16*  S1T   = (bf16*)(scr + 0);                    // [64][8192]   1 MB
  float* s1acc = (float*)(scr + (1u << 20));          // [8192][64]   2 MB  ┐
  float* h1acc = (float*)(scr + (3u << 20));          // [8192][64]   2 MB  │ zeroed together
  float* mvacc = (float*)(scr + (5u << 20));          // [8192][128]  4 MB  ┘
  bf16*  s23T  = (bf16*)(scr + (9u << 20));           // [128][8192]  2 MB
  bf16*  W1T   = (bf16*)(scr + (11u << 20));          // [64][256]    32 KB
  bf16*  adjB  = (bf16*)(scr + (16u << 20));          // [8192][8192] 128 MiB

  // zero the 8 MB accumulator region (s1acc|h1acc|mvacc contiguous)
  zero_fill<<<2048, 256, 0, stream>>>((float4*)(scr + (1u << 20)));

  prep_w1t<<<64, 256, 0, stream>>>(W1, W1T);
  // s1 = x @ W1
  gcn_mm<64, true, false><<<dim3(64, 1), 256, 0, stream>>>(x, nullptr, FEAT, W1T, s1acc,
                                                           FEAT / BK, nullptr);
  transpose_bf16_64<<<128, 256, 0, stream>>>(s1acc, S1T);
  // h1acc = adj @ s1 ; also emits adjB = bf16(adj)
  gcn_mm<64, true, true><<<dim3(64, 16), 256, 0, stream>>>(adj, nullptr, N, S1T, h1acc,
                                                           (N / 16) / BK, adjB);
  // s23T = (relu(h1acc) @ [W2|W3])^T
  relu_w23_t<<<256, 256, 0, stream>>>(h1acc, W2, W3, s23T);
  // mvacc = adj(bf16) @ s23
  gcn_mm<128, false, false><<<dim3(64, 16), 256, 0, stream>>>(nullptr, adjB, N, s23T, mvacc,
                                                              (N / 16) / BK, nullptr);
  epilogue_mu_lv<<<4096, 256, 0, stream>>>(mvacc, mu_out, lv_out);
  // recon = mu @ mu^T
  recon_mm<<<dim3(64, 64), 256, 0, stream>>>(mu_out, recon);
}

// Round 3
// 276.584 us; speedup vs baseline: 1.0932x; 1.0509x over previous
//
#include <hip/hip_runtime.h>

typedef __bf16 bf16;
typedef __attribute__((ext_vector_type(4))) __bf16 bf16x4;
typedef __attribute__((ext_vector_type(8))) __bf16 bf16x8;
typedef __attribute__((ext_vector_type(4))) float f32x4;

#define MFMA16(a, b, c) __builtin_amdgcn_mfma_f32_16x16x32_bf16((a), (b), (c), 0, 0, 0)

constexpr int BM  = 128;
constexpr int BK  = 64;
constexpr int LDT = 72;  // padded LDS row stride in bf16 (144 B = 9*16 B: 16B-aligned, bank-spread)

constexpr int N    = 8192;
constexpr int FEAT = 256;
constexpr int HID  = 64;
constexpr int KSPLIT = 16;

// Cpart[blockIdx.y][M][NCOL] = A[M][Kslice] @ Bt[NCOL][Kslice]^T   (plain stores, no atomics)
// A is f32 (cvt->bf16 on stage) when AF32, else bf16 (Abf).
// When WRITEB, the converted bf16 A-tile is also written to Aout (each (row,k)
// is staged by exactly one block -> deterministic single full conversion).
template <int NCOL, bool AF32, bool WRITEB>
__global__ __launch_bounds__(256) void gcn_mm(const float* __restrict__ A,
                                              const bf16* __restrict__ Abf, int K,
                                              const bf16* __restrict__ Bt,
                                              float* __restrict__ Cpart, int ktiles,
                                              bf16* __restrict__ Aout) {
  __shared__ bf16 As[BM * LDT];
  __shared__ bf16 Bs[NCOL * LDT];
  const int tid = threadIdx.x;
  const int lane = tid & 63;
  const int wave = tid >> 6;
  const int i0 = blockIdx.x * BM;
  const int kbase = blockIdx.y * ktiles * BK;

  f32x4 acc[2][NCOL / 16] = {};

  for (int kt = 0; kt < ktiles; ++kt) {
    const int k0 = kbase + kt * BK;
    if constexpr (AF32) {  // stage A tile [128][64] f32 -> bf16
      const int rr = tid >> 4, c4 = tid & 15;
#pragma unroll
      for (int s = 0; s < 8; ++s) {
        const int row = rr + s * 16;
        const float4 v = *reinterpret_cast<const float4*>(&A[(size_t)(i0 + row) * K + k0 + c4 * 4]);
        bf16x4 o;
        o[0] = (bf16)v.x; o[1] = (bf16)v.y; o[2] = (bf16)v.z; o[3] = (bf16)v.w;
        *reinterpret_cast<bf16x4*>(&As[row * LDT + c4 * 4]) = o;
        if constexpr (WRITEB)
          *reinterpret_cast<bf16x4*>(&Aout[(size_t)(i0 + row) * K + k0 + c4 * 4]) = o;
      }
    } else {  // stage A tile [128][64] bf16 directly
#pragma unroll
      for (int s = 0; s < 4; ++s) {
        const int idx = tid + s * 256;
        const int row = idx >> 3, q = idx & 7;
        *reinterpret_cast<bf16x8*>(&As[row * LDT + q * 8]) =
            *reinterpret_cast<const bf16x8*>(&Abf[(size_t)(i0 + row) * K + k0 + q * 8]);
      }
    }
    {  // stage B tile [NCOL][64] bf16 (already [N][K] layout)
#pragma unroll
      for (int s = 0; s < NCOL / 32; ++s) {
        const int idx = tid + s * 256;
        const int n = idx >> 3, q = idx & 7;
        *reinterpret_cast<bf16x8*>(&Bs[n * LDT + q * 8]) =
            *reinterpret_cast<const bf16x8*>(&Bt[(size_t)n * K + k0 + q * 8]);
      }
    }
    __syncthreads();
    const int rA = wave * 32 + (lane & 15);
#pragma unroll
    for (int kk = 0; kk < 2; ++kk) {
      const int kb = kk * 32 + ((lane >> 4) << 3);
      const bf16x8 a0 = *reinterpret_cast<const bf16x8*>(&As[rA * LDT + kb]);
      const bf16x8 a1 = *reinterpret_cast<const bf16x8*>(&As[(rA + 16) * LDT + kb]);
#pragma unroll
      for (int n = 0; n < NCOL / 16; ++n) {
        const bf16x8 b = *reinterpret_cast<const bf16x8*>(&Bs[(n * 16 + (lane & 15)) * LDT + kb]);
        acc[0][n] = MFMA16(a0, b, acc[0][n]);
        acc[1][n] = MFMA16(a1, b, acc[1][n]);
      }
    }
    __syncthreads();
  }
  // C/D layout (m89-verified): col = lane&15, row = (lane>>4)*4 + reg
  float* Cp = Cpart + (size_t)blockIdx.y * N * NCOL;
  const int r4 = (lane >> 4) << 2, col = lane & 15;
#pragma unroll
  for (int m = 0; m < 2; ++m)
#pragma unroll
    for (int n = 0; n < NCOL / 16; ++n)
#pragma unroll
      for (int r = 0; r < 4; ++r)
        Cp[(size_t)(i0 + wave * 32 + m * 16 + r4 + r) * NCOL + n * 16 + col] = acc[m][n][r];
}

// W1 [256][64] f32 -> W1T [64][256] bf16
__global__ void prep_w1t(const float* __restrict__ W1, bf16* __restrict__ W1T) {
  const int idx = blockIdx.x * 256 + threadIdx.x;  // 16384 total
  const int j = idx >> 8, k = idx & 255;
  W1T[idx] = (bf16)W1[k * HID + j];
}

// s1 [8192][64] f32 -> S1T [64][8192] bf16 (tile-transpose via LDS)
__global__ __launch_bounds__(256) void transpose_bf16_64(const float* __restrict__ in,
                                                         bf16* __restrict__ out) {
  __shared__ float t[64][65];
  const int i0 = blockIdx.x * 64;
  const int tid = threadIdx.x;
#pragma unroll
  for (int s = 0; s < 4; ++s) {
    const int idx = tid + s * 256;  // 1024 float4 chunks
    const int row = idx >> 4, c4 = idx & 15;
    const float4 v = *reinterpret_cast<const float4*>(&in[(size_t)(i0 + row) * HID + c4 * 4]);
    t[row][c4 * 4 + 0] = v.x; t[row][c4 * 4 + 1] = v.y;
    t[row][c4 * 4 + 2] = v.z; t[row][c4 * 4 + 3] = v.w;
  }
  __syncthreads();
#pragma unroll
  for (int s = 0; s < 2; ++s) {
    const int idx = tid + s * 256;  // 512 chunks of 8 bf16
    const int j = idx >> 3, q = idx & 7;
    bf16x8 o;
#pragma unroll
    for (int e = 0; e < 8; ++e) o[e] = (bf16)t[q * 8 + e][j];
    *reinterpret_cast<bf16x8*>(&out[(size_t)j * N + i0 + q * 8]) = o;
  }
}

// h1 = sum_s pB[s] ; s23T[j][i] = sum_c relu(h1[i][c]) * [W2|W3][c][j]  (j in [0,128))
__global__ __launch_bounds__(256) void reduce_relu_w23(const float* __restrict__ pB,
                                                       const float* __restrict__ W2,
                                                       const float* __restrict__ W3,
                                                       bf16* __restrict__ s23T) {
  __shared__ float Hs[64][65];
  __shared__ float Ws[64][128];
  const int i0 = blockIdx.x * 64;
  const int tid = threadIdx.x;
#pragma unroll
  for (int s = 0; s < 32; ++s) {  // stage W23: 8192 f32
    const int idx = tid + s * 256;
    const int c = idx >> 7, j = idx & 127;
    Ws[c][j] = (j < 64) ? W2[c * HID + j] : W3[c * HID + (j - 64)];
  }
#pragma unroll
  for (int s8 = 0; s8 < 16; ++s8) {  // reduce 16 partials + relu: 64x64 tile
    const int idx = tid + s8 * 256;
    const int r = idx >> 6, c = idx & 63;
    const size_t off = (size_t)(i0 + r) * HID + c;
    float a = 0.0f;
#pragma unroll
    for (int s = 0; s < KSPLIT; ++s) a += pB[(size_t)s * N * HID + off];
    Hs[r][c] = fmaxf(a, 0.0f);
  }
  __syncthreads();
  const int j = tid & 127, ih = tid >> 7;
  for (int ii = ih; ii < 64; ii += 2) {
    float a = 0.0f;
#pragma unroll
    for (int c = 0; c < 64; ++c) a += Hs[ii][c] * Ws[c][j];
    s23T[(size_t)j * N + i0 + ii] = (bf16)a;
  }
}

// mv = sum_s pC[s]  -> mu [8192][64] f32, logvar [8192][64] f32
__global__ __launch_bounds__(256) void reduce_mu_lv(const float* __restrict__ pC,
                                                    float* __restrict__ mu,
                                                    float* __restrict__ lv) {
  const int idx = blockIdx.x * 256 + threadIdx.x;  // 262144 threads, 4 elems each
  const int g4 = idx * 4;
  const int i = g4 >> 7, j = g4 & 127;
  float4 a = {0.f, 0.f, 0.f, 0.f};
#pragma unroll
  for (int s = 0; s < KSPLIT; ++s) {
    const float4 v = *reinterpret_cast<const float4*>(&pC[(size_t)s * N * 2 * HID + g4]);
    a.x += v.x; a.y += v.y; a.z += v.z; a.w += v.w;
  }
  float* dst = (j < 64) ? &mu[i * HID + j] : &lv[i * HID + (j - 64)];
  *reinterpret_cast<float4*>(dst) = a;
}

// recon[i][j] = dot(mu[i,:], mu[j,:]) ; mu read as f32, cvt bf16, K=64
__global__ __launch_bounds__(256) void recon_mm(const float* __restrict__ mu,
                                                float* __restrict__ out) {
  __shared__ bf16 Am[BM * LDT];
  __shared__ bf16 Bm[BM * LDT];
  const int tid = threadIdx.x, lane = tid & 63, wave = tid >> 6;
  const int i0 = blockIdx.x * 128, j0 = blockIdx.y * 128;
  {
    const int rr = tid >> 4, c4 = tid & 15;
#pragma unroll
    for (int s = 0; s < 8; ++s) {
      const int row = rr + s * 16;
      const float4 v = *reinterpret_cast<const float4*>(&mu[(size_t)(i0 + row) * HID + c4 * 4]);
      bf16x4 o;
      o[0] = (bf16)v.x; o[1] = (bf16)v.y; o[2] = (bf16)v.z; o[3] = (bf16)v.w;
      *reinterpret_cast<bf16x4*>(&Am[row * LDT + c4 * 4]) = o;
      const float4 w = *reinterpret_cast<const float4*>(&mu[(size_t)(j0 + row) * HID + c4 * 4]);
      bf16x4 p;
      p[0] = (bf16)w.x; p[1] = (bf16)w.y; p[2] = (bf16)w.z; p[3] = (bf16)w.w;
      *reinterpret_cast<bf16x4*>(&Bm[row * LDT + c4 * 4]) = p;
    }
  }
  __syncthreads();
  f32x4 acc[2][8] = {};
  const int rA = wave * 32 + (lane & 15);
#pragma unroll
  for (int kk = 0; kk < 2; ++kk) {
    const int kb = kk * 32 + ((lane >> 4) << 3);
    const bf16x8 a0 = *reinterpret_cast<const bf16x8*>(&Am[rA * LDT + kb]);
    const bf16x8 a1 = *reinterpret_cast<const bf16x8*>(&Am[(rA + 16) * LDT + kb]);
#pragma unroll
    for (int n = 0; n < 8; ++n) {
      const bf16x8 b = *reinterpret_cast<const bf16x8*>(&Bm[(n * 16 + (lane & 15)) * LDT + kb]);
      acc[0][n] = MFMA16(a0, b, acc[0][n]);
      acc[1][n] = MFMA16(a1, b, acc[1][n]);
    }
  }
  const int r4 = (lane >> 4) << 2, c = lane & 15;
#pragma unroll
  for (int m = 0; m < 2; ++m)
#pragma unroll
    for (int n = 0; n < 8; ++n)
#pragma unroll
      for (int r = 0; r < 4; ++r)
        out[(size_t)(i0 + wave * 32 + m * 16 + r4 + r) * N + j0 + n * 16 + c] = acc[m][n][r];
}

extern "C" void kernel_launch(void* const* d_in, const int* in_sizes, int n_in, void* d_out,
                              int out_size, void* d_ws, size_t ws_size, hipStream_t stream) {
  const float* x   = (const float*)d_in[0];
  const float* adj = (const float*)d_in[1];
  const float* W1  = (const float*)d_in[2];
  const float* W2  = (const float*)d_in[3];
  const float* W3  = (const float*)d_in[4];

  float* out    = (float*)d_out;
  float* recon  = out;                          // [8192][8192]  268.4 MB
  float* mu_out = out + (size_t)N * N;          // [8192][64]    (outside recon region)
  float* lv_out = mu_out + (size_t)N * HID;     // [8192][64]

  // Scratch lives inside the recon region of d_out (first 230 MB of 268 MB):
  // every scratch buffer is dead before recon_mm overwrites the region.
  // recon_mm reads only mu_out, which is outside the recon region.
  char* scr    = (char*)d_out;
  bf16*  S1T   = (bf16*)(scr + 0);                      // [64][8192]        1 MB
  float* s1acc = (float*)(scr + (1u << 20));            // [8192][64]        2 MB
  bf16*  s23T  = (bf16*)(scr + (3u << 20));             // [128][8192]       2 MB
  bf16*  W1T   = (bf16*)(scr + (5u << 20));             // [64][256]         32 KB
  float* pB    = (float*)(scr + (6u << 20));            // [16][8192][64]   32 MB
  float* pC    = (float*)(scr + (38u << 20));           // [16][8192][128]  64 MB
  bf16*  adjB  = (bf16*)(scr + (102u << 20));           // [8192][8192]    128 MB -> ends at 230 MB

  prep_w1t<<<64, 256, 0, stream>>>(W1, W1T);
  // s1 = x @ W1   (single split -> direct store)
  gcn_mm<64, true, false><<<dim3(64, 1), 256, 0, stream>>>(x, nullptr, FEAT, W1T, s1acc,
                                                           FEAT / BK, nullptr);
  transpose_bf16_64<<<128, 256, 0, stream>>>(s1acc, S1T);
  // pB[s] = adj_slice @ s1 ; also emits adjB = bf16(adj)
  gcn_mm<64, true, true><<<dim3(64, KSPLIT), 256, 0, stream>>>(adj, nullptr, N, S1T, pB,
                                                               (N / KSPLIT) / BK, adjB);
  // s23T = (relu(sum_s pB[s]) @ [W2|W3])^T
  reduce_relu_w23<<<128, 256, 0, stream>>>(pB, W2, W3, s23T);
  // pC[s] = adjB_slice @ s23
  gcn_mm<128, false, false><<<dim3(64, KSPLIT), 256, 0, stream>>>(nullptr, adjB, N, s23T, pC,
                                                                  (N / KSPLIT) / BK, nullptr);
  reduce_mu_lv<<<1024, 256, 0, stream>>>(pC, mu_out, lv_out);
  // recon = mu @ mu^T
  recon_mm<<<dim3(64, 64), 256, 0, stream>>>(mu_out, recon);
}

// Round 5
// 268.214 us; speedup vs baseline: 1.1273x; 1.0312x over previous
//
#include <hip/hip_runtime.h>

typedef __bf16 bf16;
typedef __attribute__((ext_vector_type(4))) __bf16 bf16x4;
typedef __attribute__((ext_vector_type(8))) __bf16 bf16x8;
typedef __attribute__((ext_vector_type(4))) float f32x4;

#define MFMA16(a, b, c) __builtin_amdgcn_mfma_f32_16x16x32_bf16((a), (b), (c), 0, 0, 0)

constexpr int BM  = 128;
constexpr int BK  = 64;
constexpr int LDT = 72;  // padded LDS row stride in bf16 (144 B = 9*16 B: 16B-aligned, bank-spread)

constexpr int N    = 8192;
constexpr int FEAT = 256;
constexpr int HID  = 64;
constexpr int KSPLIT = 8;

// adj f32 -> adjB bf16 (one clean streaming pass; adjB then fits Infinity Cache)
__global__ __launch_bounds__(256) void convert_adj(const float* __restrict__ in,
                                                   bf16* __restrict__ out) {
  const size_t stride = (size_t)gridDim.x * 256;
  const size_t nchunk = (size_t)N * N / 8;
  for (size_t c = (size_t)blockIdx.x * 256 + threadIdx.x; c < nchunk; c += stride) {
    const float4 v0 = *reinterpret_cast<const float4*>(&in[c * 8]);
    const float4 v1 = *reinterpret_cast<const float4*>(&in[c * 8 + 4]);
    bf16x8 o;
    o[0] = (bf16)v0.x; o[1] = (bf16)v0.y; o[2] = (bf16)v0.z; o[3] = (bf16)v0.w;
    o[4] = (bf16)v1.x; o[5] = (bf16)v1.y; o[6] = (bf16)v1.z; o[7] = (bf16)v1.w;
    *reinterpret_cast<bf16x8*>(&out[c * 8]) = o;
  }
}

// Cpart[blockIdx.y][M][NCOL] = A[M][Kslice] @ Bt[NCOL][Kslice]^T   (plain stores)
// A is f32 (cvt->bf16 on stage) when AF32 (pass-A on x), else bf16.
template <int NCOL, bool AF32>
__global__ __launch_bounds__(256) void gcn_mm(const float* __restrict__ A,
                                              const bf16* __restrict__ Abf, int K,
                                              const bf16* __restrict__ Bt,
                                              float* __restrict__ Cpart, int ktiles) {
  __shared__ bf16 As[BM * LDT];
  __shared__ bf16 Bs[NCOL * LDT];
  const int tid = threadIdx.x;
  const int lane = tid & 63;
  const int wave = tid >> 6;
  const int i0 = blockIdx.x * BM;
  const int kbase = blockIdx.y * ktiles * BK;

  f32x4 acc[2][NCOL / 16] = {};

  for (int kt = 0; kt < ktiles; ++kt) {
    const int k0 = kbase + kt * BK;
    if constexpr (AF32) {  // stage A tile [128][64] f32 -> bf16
      const int rr = tid >> 4, c4 = tid & 15;
#pragma unroll
      for (int s = 0; s < 8; ++s) {
        const int row = rr + s * 16;
        const float4 v = *reinterpret_cast<const float4*>(&A[(size_t)(i0 + row) * K + k0 + c4 * 4]);
        bf16x4 o;
        o[0] = (bf16)v.x; o[1] = (bf16)v.y; o[2] = (bf16)v.z; o[3] = (bf16)v.w;
        *reinterpret_cast<bf16x4*>(&As[row * LDT + c4 * 4]) = o;
      }
    } else {  // stage A tile [128][64] bf16 directly
#pragma unroll
      for (int s = 0; s < 4; ++s) {
        const int idx = tid + s * 256;
        const int row = idx >> 3, q = idx & 7;
        *reinterpret_cast<bf16x8*>(&As[row * LDT + q * 8]) =
            *reinterpret_cast<const bf16x8*>(&Abf[(size_t)(i0 + row) * K + k0 + q * 8]);
      }
    }
    {  // stage B tile [NCOL][64] bf16 (already [N][K] layout)
#pragma unroll
      for (int s = 0; s < NCOL / 32; ++s) {
        const int idx = tid + s * 256;
        const int n = idx >> 3, q = idx & 7;
        *reinterpret_cast<bf16x8*>(&Bs[n * LDT + q * 8]) =
            *reinterpret_cast<const bf16x8*>(&Bt[(size_t)n * K + k0 + q * 8]);
      }
    }
    __syncthreads();
    const int rA = wave * 32 + (lane & 15);
#pragma unroll
    for (int kk = 0; kk < 2; ++kk) {
      const int kb = kk * 32 + ((lane >> 4) << 3);
      const bf16x8 a0 = *reinterpret_cast<const bf16x8*>(&As[rA * LDT + kb]);
      const bf16x8 a1 = *reinterpret_cast<const bf16x8*>(&As[(rA + 16) * LDT + kb]);
#pragma unroll
      for (int n = 0; n < NCOL / 16; ++n) {
        const bf16x8 b = *reinterpret_cast<const bf16x8*>(&Bs[(n * 16 + (lane & 15)) * LDT + kb]);
        acc[0][n] = MFMA16(a0, b, acc[0][n]);
        acc[1][n] = MFMA16(a1, b, acc[1][n]);
      }
    }
    __syncthreads();
  }
  // C/D layout (m89-verified): col = lane&15, row = (lane>>4)*4 + reg
  float* Cp = Cpart + (size_t)blockIdx.y * N * NCOL;
  const int r4 = (lane >> 4) << 2, col = lane & 15;
#pragma unroll
  for (int m = 0; m < 2; ++m)
#pragma unroll
    for (int n = 0; n < NCOL / 16; ++n)
#pragma unroll
      for (int r = 0; r < 4; ++r)
        Cp[(size_t)(i0 + wave * 32 + m * 16 + r4 + r) * NCOL + n * 16 + col] = acc[m][n][r];
}

// W1 [256][64] f32 -> W1T [64][256] bf16
__global__ void prep_w1t(const float* __restrict__ W1, bf16* __restrict__ W1T) {
  const int idx = blockIdx.x * 256 + threadIdx.x;  // 16384 total
  const int j = idx >> 8, k = idx & 255;
  W1T[idx] = (bf16)W1[k * HID + j];
}

// s1 [8192][64] f32 -> S1T [64][8192] bf16 (tile-transpose via LDS)
__global__ __launch_bounds__(256) void transpose_bf16_64(const float* __restrict__ in,
                                                         bf16* __restrict__ out) {
  __shared__ float t[64][65];
  const int i0 = blockIdx.x * 64;
  const int tid = threadIdx.x;
#pragma unroll
  for (int s = 0; s < 4; ++s) {
    const int idx = tid + s * 256;  // 1024 float4 chunks
    const int row = idx >> 4, c4 = idx & 15;
    const float4 v = *reinterpret_cast<const float4*>(&in[(size_t)(i0 + row) * HID + c4 * 4]);
    t[row][c4 * 4 + 0] = v.x; t[row][c4 * 4 + 1] = v.y;
    t[row][c4 * 4 + 2] = v.z; t[row][c4 * 4 + 3] = v.w;
  }
  __syncthreads();
#pragma unroll
  for (int s = 0; s < 2; ++s) {
    const int idx = tid + s * 256;  // 512 chunks of 8 bf16
    const int j = idx >> 3, q = idx & 7;
    bf16x8 o;
#pragma unroll
    for (int e = 0; e < 8; ++e) o[e] = (bf16)t[q * 8 + e][j];
    *reinterpret_cast<bf16x8*>(&out[(size_t)j * N + i0 + q * 8]) = o;
  }
}

// h1 = sum_s pB[s] ; s23T[j][i] = sum_c relu(h1[i][c]) * [W2|W3][c][j]  (j in [0,128))
__global__ __launch_bounds__(256) void reduce_relu_w23(const float* __restrict__ pB,
                                                       const float* __restrict__ W2,
                                                       const float* __restrict__ W3,
                                                       bf16* __restrict__ s23T) {
  __shared__ float Hs[64][65];
  __shared__ float Ws[64][128];
  const int i0 = blockIdx.x * 64;
  const int tid = threadIdx.x;
#pragma unroll
  for (int s = 0; s < 32; ++s) {  // stage W23: 8192 f32
    const int idx = tid + s * 256;
    const int c = idx >> 7, j = idx & 127;
    Ws[c][j] = (j < 64) ? W2[c * HID + j] : W3[c * HID + (j - 64)];
  }
#pragma unroll
  for (int s8 = 0; s8 < 16; ++s8) {  // reduce partials + relu: 64x64 tile
    const int idx = tid + s8 * 256;
    const int r = idx >> 6, c = idx & 63;
    const size_t off = (size_t)(i0 + r) * HID + c;
    float a = 0.0f;
#pragma unroll
    for (int s = 0; s < KSPLIT; ++s) a += pB[(size_t)s * N * HID + off];
    Hs[r][c] = fmaxf(a, 0.0f);
  }
  __syncthreads();
  const int j = tid & 127, ih = tid >> 7;
  for (int ii = ih; ii < 64; ii += 2) {
    float a = 0.0f;
#pragma unroll
    for (int c = 0; c < 64; ++c) a += Hs[ii][c] * Ws[c][j];
    s23T[(size_t)j * N + i0 + ii] = (bf16)a;
  }
}

// mv = sum_s pC[s]  -> mu [8192][64] f32, logvar [8192][64] f32
__global__ __launch_bounds__(256) void reduce_mu_lv(const float* __restrict__ pC,
                                                    float* __restrict__ mu,
                                                    float* __restrict__ lv) {
  const int idx = blockIdx.x * 256 + threadIdx.x;  // 262144 threads, 4 elems each
  const int g4 = idx * 4;
  const int i = g4 >> 7, j = g4 & 127;
  float4 a = {0.f, 0.f, 0.f, 0.f};
#pragma unroll
  for (int s = 0; s < KSPLIT; ++s) {
    const float4 v = *reinterpret_cast<const float4*>(&pC[(size_t)s * N * 2 * HID + g4]);
    a.x += v.x; a.y += v.y; a.z += v.z; a.w += v.w;
  }
  float* dst = (j < 64) ? &mu[i * HID + j] : &lv[i * HID + (j - 64)];
  *reinterpret_cast<float4*>(dst) = a;
}

// recon[i][j] = dot(mu[i,:], mu[j,:]) ; mu read as f32, cvt bf16, K=64
__global__ __launch_bounds__(256) void recon_mm(const float* __restrict__ mu,
                                                float* __restrict__ out) {
  __shared__ bf16 Am[BM * LDT];
  __shared__ bf16 Bm[BM * LDT];
  const int tid = threadIdx.x, lane = tid & 63, wave = tid >> 6;
  const int i0 = blockIdx.x * 128, j0 = blockIdx.y * 128;
  {
    const int rr = tid >> 4, c4 = tid & 15;
#pragma unroll
    for (int s = 0; s < 8; ++s) {
      const int row = rr + s * 16;
      const float4 v = *reinterpret_cast<const float4*>(&mu[(size_t)(i0 + row) * HID + c4 * 4]);
      bf16x4 o;
      o[0] = (bf16)v.x; o[1] = (bf16)v.y; o[2] = (bf16)v.z; o[3] = (bf16)v.w;
      *reinterpret_cast<bf16x4*>(&Am[row * LDT + c4 * 4]) = o;
      const float4 w = *reinterpret_cast<const float4*>(&mu[(size_t)(j0 + row) * HID + c4 * 4]);
      bf16x4 p;
      p[0] = (bf16)w.x; p[1] = (bf16)w.y; p[2] = (bf16)w.z; p[3] = (bf16)w.w;
      *reinterpret_cast<bf16x4*>(&Bm[row * LDT + c4 * 4]) = p;
    }
  }
  __syncthreads();
  f32x4 acc[2][8] = {};
  const int rA = wave * 32 + (lane & 15);
#pragma unroll
  for (int kk = 0; kk < 2; ++kk) {
    const int kb = kk * 32 + ((lane >> 4) << 3);
    const bf16x8 a0 = *reinterpret_cast<const bf16x8*>(&Am[rA * LDT + kb]);
    const bf16x8 a1 = *reinterpret_cast<const bf16x8*>(&Am[(rA + 16) * LDT + kb]);
#pragma unroll
    for (int n = 0; n < 8; ++n) {
      const bf16x8 b = *reinterpret_cast<const bf16x8*>(&Bm[(n * 16 + (lane & 15)) * LDT + kb]);
      acc[0][n] = MFMA16(a0, b, acc[0][n]);
      acc[1][n] = MFMA16(a1, b, acc[1][n]);
    }
  }
  const int r4 = (lane >> 4) << 2, c = lane & 15;
#pragma unroll
  for (int m = 0; m < 2; ++m)
#pragma unroll
    for (int n = 0; n < 8; ++n)
#pragma unroll
      for (int r = 0; r < 4; ++r)
        out[(size_t)(i0 + wave * 32 + m * 16 + r4 + r) * N + j0 + n * 16 + c] = acc[m][n][r];
}

extern "C" void kernel_launch(void* const* d_in, const int* in_sizes, int n_in, void* d_out,
                              int out_size, void* d_ws, size_t ws_size, hipStream_t stream) {
  const float* x   = (const float*)d_in[0];
  const float* adj = (const float*)d_in[1];
  const float* W1  = (const float*)d_in[2];
  const float* W2  = (const float*)d_in[3];
  const float* W3  = (const float*)d_in[4];

  float* out    = (float*)d_out;
  float* recon  = out;                          // [8192][8192]  256 MiB
  float* mu_out = out + (size_t)N * N;          // [8192][64]    (outside recon region)
  float* lv_out = mu_out + (size_t)N * HID;     // [8192][64]

  // Scratch lives inside the recon region of d_out (<= 230 MiB < 256 MiB):
  // every scratch buffer is dead before recon_mm overwrites the region
  // (recon_mm reads only mu_out, which is outside it). d_out total = 260 MiB.
  char* scr    = (char*)d_out;
  bf16*  S1T   = (bf16*)(scr + 0);                      // [64][8192]        1 MB
  float* s1acc = (float*)(scr + (1u << 20));            // [8192][64]        2 MB
  bf16*  s23T  = (bf16*)(scr + (3u << 20));             // [128][8192]       2 MB
  bf16*  W1T   = (bf16*)(scr + (5u << 20));             // [64][256]         32 KB
  float* pB    = (float*)(scr + (6u << 20));            // [8][8192][64]    16 MB -> ends 22 MiB
  float* pC    = (float*)(scr + (22u << 20));           // [8][8192][128]   32 MB -> ends 54 MiB
  bf16*  adjB  = (bf16*)(scr + (102u << 20));           // [8192][8192]    128 MiB -> ends 230 MiB

  // adjB = bf16(adj): single streaming conversion; adjB (134 MB) fits L3,
  // so both adj GEMM passes below read L3-hot bf16 data.
  convert_adj<<<2048, 256, 0, stream>>>(adj, adjB);

  prep_w1t<<<64, 256, 0, stream>>>(W1, W1T);
  // s1 = x @ W1   (single split -> direct store)
  gcn_mm<64, true><<<dim3(64, 1), 256, 0, stream>>>(x, nullptr, FEAT, W1T, s1acc, FEAT / BK);
  transpose_bf16_64<<<128, 256, 0, stream>>>(s1acc, S1T);
  // pB[s] = adjB_slice @ s1
  gcn_mm<64, false><<<dim3(64, KSPLIT), 256, 0, stream>>>(nullptr, adjB, N, S1T, pB,
                                                          (N / KSPLIT) / BK);
  // s23T = (relu(sum_s pB[s]) @ [W2|W3])^T
  reduce_relu_w23<<<128, 256, 0, stream>>>(pB, W2, W3, s23T);
  // pC[s] = adjB_slice @ s23
  gcn_mm<128, false><<<dim3(64, KSPLIT), 256, 0, stream>>>(nullptr, adjB, N, s23T, pC,
                                                           (N / KSPLIT) / BK);
  reduce_mu_lv<<<1024, 256, 0, stream>>>(pC, mu_out, lv_out);
  // recon = mu @ mu^T
  recon_mm<<<dim3(64, 64), 256, 0, stream>>>(mu_out, recon);
}